// Round 3
// baseline (1156.849 us; speedup 1.0000x reference)
//
#include <hip/hip_runtime.h>
#include <cstdint>
#include <cstddef>

#define HID 512
#define BATCH 4096
#define T_STEPS 20

typedef unsigned short ushort_t;
typedef __attribute__((ext_vector_type(8))) __bf16 bf16x8;
typedef __attribute__((ext_vector_type(4))) float f32x4;

typedef __attribute__((address_space(1))) void gvoid;
typedef __attribute__((address_space(3))) void lvoid;

// fp32 -> bf16 round-to-nearest-even (finite inputs only)
__device__ __forceinline__ unsigned short f2bf(float f) {
  unsigned int u = __float_as_uint(f);
  u += 0x7FFFu + ((u >> 16) & 1u);
  return (unsigned short)(u >> 16);
}

__device__ __forceinline__ float wave_max(float v) {
#pragma unroll
  for (int off = 32; off > 0; off >>= 1) v = fmaxf(v, __shfl_xor(v, off));
  return v;
}
__device__ __forceinline__ float wave_sum(float v) {
#pragma unroll
  for (int off = 32; off > 0; off >>= 1) v += __shfl_xor(v, off);
  return v;
}

// async global->LDS, 16B per lane. lds ptr must be wave-uniform (lane*16 is added by HW).
__device__ __forceinline__ void load_lds16(const void* g, void* l) {
  __builtin_amdgcn_global_load_lds((gvoid*)g, (lvoid*)l, 16, 0, 0);
}

// ---------------------------------------------------------------------------
// Fused gate GEMM + activation, 2-phase double-buffered pipeline.
// dh = sigmoid(Lo) * tanh(sigmoid(Li)*tanh(Lg)),  L* = zb @ W*^T
// Wcat = [Wi;Wg;Wo] row-major. Tiles BM=64 x BN=128, BK=32; 4 waves 2x2;
// wave tile 32x64; 24 MFMA / k-iter / wave. Stage k+1 issued BEFORE compute
// of k; single barrier per k-iter (its implicit vmcnt(0) drains the stage).
// ---------------------------------------------------------------------------
__global__ __launch_bounds__(256) void gemm_gates(
    const ushort_t* __restrict__ A,   // zb [4096,512] bf16
    const ushort_t* __restrict__ W,   // Wcat [3*512,512] bf16
    ushort_t* __restrict__ dh) {
  constexpr int K = HID;
  constexpr int BM = 64, BN = 128, BK = 32;
  constexpr int WM = 32, WN = 64, FM = 2, FN = 4;
  constexpr int NT = K / BK;  // 16

  __shared__ ushort_t As[2][BM * BK];     // 2 x 4 KB
  __shared__ ushort_t Bs[2][3][BN * BK];  // 2 x 24 KB

  const int tid = threadIdx.x;
  const int wave = tid >> 6;
  const int lane = tid & 63;
  const int quad = lane >> 4;
  const int l16 = lane & 15;

  const int m0 = blockIdx.x * BM;
  const int n0 = blockIdx.y * BN;
  const int wm = (wave & 1) * WM;
  const int wn = (wave >> 1) * WN;

  f32x4 acc[3][FM][FN] = {};

  const ushort_t* Ag = A + (size_t)m0 * K;

  // staging geometry: 4 lanes cover one 32-col row (4 x 16B)
  const int lbA = wave * 64;
  const int rowA = (lbA + lane) >> 2;
  const int kcA = (lbA + lane) & 3;

  auto stage = [&](int b, int k0) {
    load_lds16(Ag + (size_t)rowA * K + k0 + kcA * 8, &As[b][lbA * 8]);
#pragma unroll
    for (int g = 0; g < 3; ++g) {
      const ushort_t* Bg = W + (size_t)g * HID * K + (size_t)n0 * K;
#pragma unroll
      for (int q = 0; q < 2; ++q) {
        int lb = q * 256 + wave * 64;
        int linear = lb + lane;
        int row = linear >> 2;
        int kc = linear & 3;
        load_lds16(Bg + (size_t)row * K + k0 + kc * 8, &Bs[b][g][lb * 8]);
      }
    }
  };

  auto compute = [&](int b) {
    bf16x8 af[FM];
#pragma unroll
    for (int i = 0; i < FM; ++i)
      af[i] = *(const bf16x8*)&As[b][(wm + i * 16 + l16) * BK + quad * 8];
#pragma unroll
    for (int g = 0; g < 3; ++g) {
      bf16x8 bfr[FN];
#pragma unroll
      for (int j = 0; j < FN; ++j)
        bfr[j] = *(const bf16x8*)&Bs[b][g][(wn + j * 16 + l16) * BK + quad * 8];
#pragma unroll
      for (int i = 0; i < FM; ++i)
#pragma unroll
        for (int j = 0; j < FN; ++j)
          acc[g][i][j] = __builtin_amdgcn_mfma_f32_16x16x32_bf16(af[i], bfr[j], acc[g][i][j], 0, 0, 0);
    }
  };

  stage(0, 0);
  __syncthreads();

#pragma unroll 1
  for (int t = 0; t < NT; t += 2) {
    // phase A: prefetch slice t+1 into buf1, compute slice t from buf0
    if (t + 1 < NT) stage(1, (t + 1) * BK);
    compute(0);
    __syncthreads();  // drains this phase's stage (vmcnt 0) + protects buf0
    // phase B: prefetch slice t+2 into buf0, compute slice t+1 from buf1
    if (t + 2 < NT) stage(0, (t + 2) * BK);
    compute(1);
    __syncthreads();
  }

  // Epilogue: activation in-register; C/D layout col=lane&15, row=quad*4+reg.
#pragma unroll
  for (int i = 0; i < FM; ++i)
#pragma unroll
    for (int j = 0; j < FN; ++j) {
      int row = m0 + wm + i * 16 + quad * 4;
      int col = n0 + wn + j * 16 + l16;
#pragma unroll
      for (int r = 0; r < 4; ++r) {
        float gi = 1.f / (1.f + expf(-acc[0][i][j][r]));
        float gg = tanhf(acc[1][i][j][r]);
        float go = 1.f / (1.f + expf(-acc[2][i][j][r]));
        dh[(size_t)(row + r) * HID + col] = f2bf(go * tanhf(gi * gg));
      }
    }
}

// ---------------------------------------------------------------------------
// Fused Wout GEMM + euler update + output projection.
// Block = 16 full rows (BM=16, BN=512), grid 256, 512 threads = 8 waves
// (2 waves/SIMD for latency hiding). Wave w owns cols [w*64, w*64+64):
// FN=4 MFMA col-fragments. A slice (16 KB) L1-resident; Wout (512 KB)
// L2-resident, each fragment consumed once -> direct global->VGPR loads,
// no LDS staging, no barriers in the main loop.
// Epilogue: row-softmax(+bout), euler z-update, zb cast, softmax(zn)·Wfc.
// ---------------------------------------------------------------------------
__global__ __launch_bounds__(512) void gemm_update(
    const ushort_t* __restrict__ A,   // dh [4096,512] bf16
    const ushort_t* __restrict__ W,   // WoutB [512,512] bf16
    const float* __restrict__ bout,
    float* __restrict__ z, ushort_t* __restrict__ zb,
    const float* __restrict__ Wfc, const float* __restrict__ bfc,
    const float* __restrict__ ts, float* __restrict__ out, int t) {
  constexpr int K = HID;
  constexpr int FN = 4;
  constexpr int NW = 8;  // waves

  const int tid = threadIdx.x;
  const int wave = tid >> 6;   // 0..7
  const int lane = tid & 63;
  const int quad = lane >> 4;
  const int l16 = lane & 15;

  const int m0 = blockIdx.x * 16;
  const int wn = wave * 64;

  f32x4 acc[FN] = {};

  const ushort_t* Arow = A + (size_t)(m0 + l16) * K + quad * 8;

#pragma unroll 4
  for (int k0 = 0; k0 < K; k0 += 32) {
    bf16x8 af = *(const bf16x8*)(Arow + k0);
#pragma unroll
    for (int j = 0; j < FN; ++j) {
      int col = wn + j * 16 + l16;
      bf16x8 bf = *(const bf16x8*)(W + (size_t)col * K + k0 + quad * 8);
      acc[j] = __builtin_amdgcn_mfma_f32_16x16x32_bf16(af, bf, acc[j], 0, 0, 0);
    }
  }

  // ---- epilogue: lane holds rows (quad*4+r), cols (wn + j*16 + l16) ----
  const float dtv = ts[t + 1] - ts[t];

#pragma unroll
  for (int j = 0; j < FN; ++j) {
    float bo = bout[wn + j * 16 + l16];
#pragma unroll
    for (int r = 0; r < 4; ++r) acc[j][r] += bo;
  }

  __shared__ float rmax1[NW][16];
  __shared__ float rsum1[NW][16];
  __shared__ float rmax2[NW][16];
  __shared__ float rsd[NW][16][2];

  // row max (512-wide): per-lane over j, shfl over 16 lanes, LDS over 8 waves
  float m1[4];
#pragma unroll
  for (int r = 0; r < 4; ++r) {
    float m = acc[0][r];
#pragma unroll
    for (int j = 1; j < FN; ++j) m = fmaxf(m, acc[j][r]);
#pragma unroll
    for (int off = 1; off < 16; off <<= 1) m = fmaxf(m, __shfl_xor(m, off));
    m1[r] = m;
  }
  if (l16 == 0) {
#pragma unroll
    for (int r = 0; r < 4; ++r) rmax1[wave][quad * 4 + r] = m1[r];
  }
  __syncthreads();
#pragma unroll
  for (int r = 0; r < 4; ++r) {
    int row = quad * 4 + r;
    float m = rmax1[0][row];
#pragma unroll
    for (int w = 1; w < NW; ++w) m = fmaxf(m, rmax1[w][row]);
    m1[r] = m;
  }

  // exp (in place) + row sum
  float s1[4] = {0.f, 0.f, 0.f, 0.f};
#pragma unroll
  for (int j = 0; j < FN; ++j)
#pragma unroll
    for (int r = 0; r < 4; ++r) {
      float e = expf(acc[j][r] - m1[r]);
      acc[j][r] = e;
      s1[r] += e;
    }
#pragma unroll
  for (int r = 0; r < 4; ++r) {
#pragma unroll
    for (int off = 1; off < 16; off <<= 1) s1[r] += __shfl_xor(s1[r], off);
  }
  if (l16 == 0) {
#pragma unroll
    for (int r = 0; r < 4; ++r) rsum1[wave][quad * 4 + r] = s1[r];
  }
  __syncthreads();
  float inv1[4];
#pragma unroll
  for (int r = 0; r < 4; ++r) {
    int row = quad * 4 + r;
    float s = rsum1[0][row];
#pragma unroll
    for (int w = 1; w < NW; ++w) s += rsum1[w][row];
    inv1[r] = 1.f / s;
  }

  // zn = z + dt * softmax  (in place into acc); write z, zb
#pragma unroll
  for (int j = 0; j < FN; ++j) {
    int col = wn + j * 16 + l16;
#pragma unroll
    for (int r = 0; r < 4; ++r) {
      size_t idx = (size_t)(m0 + quad * 4 + r) * HID + col;
      float zn = z[idx] + dtv * acc[j][r] * inv1[r];
      acc[j][r] = zn;
      z[idx] = zn;
      zb[idx] = f2bf(zn);
    }
  }

  // second softmax over zn + dot with Wfc
  float m2[4];
#pragma unroll
  for (int r = 0; r < 4; ++r) {
    float m = acc[0][r];
#pragma unroll
    for (int j = 1; j < FN; ++j) m = fmaxf(m, acc[j][r]);
#pragma unroll
    for (int off = 1; off < 16; off <<= 1) m = fmaxf(m, __shfl_xor(m, off));
    m2[r] = m;
  }
  if (l16 == 0) {
#pragma unroll
    for (int r = 0; r < 4; ++r) rmax2[wave][quad * 4 + r] = m2[r];
  }
  __syncthreads();
#pragma unroll
  for (int r = 0; r < 4; ++r) {
    int row = quad * 4 + r;
    float m = rmax2[0][row];
#pragma unroll
    for (int w = 1; w < NW; ++w) m = fmaxf(m, rmax2[w][row]);
    m2[r] = m;
  }

  float s2[4] = {0.f, 0.f, 0.f, 0.f};
  float dd[4] = {0.f, 0.f, 0.f, 0.f};
#pragma unroll
  for (int j = 0; j < FN; ++j) {
    float w = Wfc[wn + j * 16 + l16];
#pragma unroll
    for (int r = 0; r < 4; ++r) {
      float e = expf(acc[j][r] - m2[r]);
      s2[r] += e;
      dd[r] += e * w;
    }
  }
#pragma unroll
  for (int r = 0; r < 4; ++r) {
#pragma unroll
    for (int off = 1; off < 16; off <<= 1) {
      s2[r] += __shfl_xor(s2[r], off);
      dd[r] += __shfl_xor(dd[r], off);
    }
  }
  if (l16 == 0) {
#pragma unroll
    for (int r = 0; r < 4; ++r) {
      rsd[wave][quad * 4 + r][0] = s2[r];
      rsd[wave][quad * 4 + r][1] = dd[r];
    }
  }
  __syncthreads();
  if (wave == 0 && l16 == 0) {
    float bfc0 = bfc[0];
#pragma unroll
    for (int r = 0; r < 4; ++r) {
      int row = quad * 4 + r;
      float ss = 0.f, dv = 0.f;
#pragma unroll
      for (int w = 0; w < NW; ++w) { ss += rsd[w][row][0]; dv += rsd[w][row][1]; }
      out[(size_t)(m0 + row) * T_STEPS + t + 1] = dv / ss + bfc0;
    }
  }
}

// weights fp32 -> bf16; Wcat = [Wi; Wg; Wo] (each 512x512, row-major => flat concat)
__global__ __launch_bounds__(256) void convw_kernel(
    const float* __restrict__ Wi, const float* __restrict__ Wg,
    const float* __restrict__ Wo, const float* __restrict__ Wout,
    ushort_t* __restrict__ Wcat, ushort_t* __restrict__ WoutB) {
  const int nW = HID * HID;  // 262144
  int e = (blockIdx.x * 256 + threadIdx.x) * 4;  // 1024 blocks covers 4*nW
  const float* src;
  ushort_t* dst;
  if (e < nW)            { src = Wi + e;          dst = Wcat + e; }
  else if (e < 2 * nW)   { src = Wg + (e - nW);   dst = Wcat + e; }
  else if (e < 3 * nW)   { src = Wo + (e - 2*nW); dst = Wcat + e; }
  else                   { src = Wout + (e - 3*nW); dst = WoutB + (e - 3*nW); }
  float4 v = *(const float4*)src;
  union { unsigned short us[4]; uint2 u; } p;
  p.us[0] = f2bf(v.x); p.us[1] = f2bf(v.y); p.us[2] = f2bf(v.z); p.us[3] = f2bf(v.w);
  *(uint2*)dst = p.u;
}

// z = y ; zb = bf16(y) ; out[:,0] = softmax(y)·Wfc + bfc   (one wave per row)
__global__ __launch_bounds__(256) void init_kernel(
    const float* __restrict__ y, float* __restrict__ z, ushort_t* __restrict__ zb,
    const float* __restrict__ Wfc, const float* __restrict__ bfc,
    float* __restrict__ out) {
  const int wave = threadIdx.x >> 6;
  const int lane = threadIdx.x & 63;
  const int row = blockIdx.x * 4 + wave;
  const float4* y4 = (const float4*)(y + (size_t)row * HID);
  float4 v0 = y4[lane * 2];
  float4 v1 = y4[lane * 2 + 1];
  float zn[8] = {v0.x, v0.y, v0.z, v0.w, v1.x, v1.y, v1.z, v1.w};
  float4* z4 = (float4*)(z + (size_t)row * HID);
  z4[lane * 2] = v0;
  z4[lane * 2 + 1] = v1;
  union { unsigned short us[8]; uint4 v; } p;
#pragma unroll
  for (int i = 0; i < 8; ++i) p.us[i] = f2bf(zn[i]);
  *(uint4*)(zb + (size_t)row * HID + lane * 8) = p.v;

  const float4* w4 = (const float4*)Wfc;
  float4 w0 = w4[lane * 2], w1 = w4[lane * 2 + 1];
  float w[8] = {w0.x, w0.y, w0.z, w0.w, w1.x, w1.y, w1.z, w1.w};
  float m = zn[0];
#pragma unroll
  for (int i = 1; i < 8; ++i) m = fmaxf(m, zn[i]);
  m = wave_max(m);
  float s = 0.f, d = 0.f;
#pragma unroll
  for (int i = 0; i < 8; ++i) { float e = expf(zn[i] - m); s += e; d += e * w[i]; }
  s = wave_sum(s);
  d = wave_sum(d);
  if (lane == 0) out[(size_t)row * T_STEPS] = d / s + bfc[0];
}

extern "C" void kernel_launch(void* const* d_in, const int* in_sizes, int n_in,
                              void* d_out, int out_size, void* d_ws, size_t ws_size,
                              hipStream_t stream) {
  const float* y    = (const float*)d_in[0];
  const float* ts   = (const float*)d_in[1];
  const float* Wi   = (const float*)d_in[2];
  // d_in[3] = Wf: computed-but-unused in reference -> skipped
  const float* Wg   = (const float*)d_in[4];
  const float* Wo   = (const float*)d_in[5];
  const float* Wout = (const float*)d_in[6];
  const float* bout = (const float*)d_in[7];
  const float* Wfc  = (const float*)d_in[8];
  const float* bfc  = (const float*)d_in[9];
  float* out = (float*)d_out;

  // workspace layout (bytes), all 256-aligned
  char* ws = (char*)d_ws;
  float*    z     = (float*)(ws);                      // 4096*512*4  = 8388608
  ushort_t* zb    = (ushort_t*)(ws + 8388608);         // 4096*512*2  = 4194304
  ushort_t* dh    = (ushort_t*)(ws + 12582912);        // 4096*512*2  = 4194304
  ushort_t* Wcat  = (ushort_t*)(ws + 41943040);        // 1536*512*2  = 1572864
  ushort_t* WoutB = (ushort_t*)(ws + 43515904);        // 512*512*2   = 524288

  convw_kernel<<<1024, 256, 0, stream>>>(Wi, Wg, Wo, Wout, Wcat, WoutB);
  init_kernel<<<BATCH / 4, 256, 0, stream>>>(y, z, zb, Wfc, bfc, out);

  for (int t = 0; t < T_STEPS - 1; ++t) {
    // fused gate logits + activation: dh = act(zb @ [Wi;Wg;Wo]^T)
    gemm_gates<<<dim3(BATCH / 64, HID / 128), 256, 0, stream>>>(zb, Wcat, dh);
    // fused dh @ Wout^T + softmax + euler update + out projection
    gemm_update<<<BATCH / 16, 512, 0, stream>>>(dh, WoutB, bout, z, zb, Wfc, bfc, ts, out, t);
  }
}